// Round 3
// baseline (297.899 us; speedup 1.0000x reference)
//
#include <hip/hip_runtime.h>
#include <hip/hip_bf16.h>
#include <math.h>

typedef __attribute__((ext_vector_type(8))) short  short8;
typedef __attribute__((ext_vector_type(4))) short  short4v;
typedef __attribute__((ext_vector_type(4))) float  floatx4;

// ---------------------------------------------------------------------------
// C[M,N] = scale * (A[M,K] * Bt[N,K]^T) + bias ; A,Bt bf16, fp32 acc.
// 128x128 tile, 4 waves (2x2), each wave 4x4 MFMA 16x16x32 tiles, BK=64.
// Conservative staging (audited): vector global loads -> regs ->
// ds_write_b128, LDS rows padded to 72 elements. Output fp32 or bf16.
// ---------------------------------------------------------------------------
template <bool OUT_BF16>
__global__ __launch_bounds__(256, 2)
void gemm_bt(const __hip_bfloat16* __restrict__ A,
             const __hip_bfloat16* __restrict__ Bt,
             const float* __restrict__ bias,
             void* __restrict__ Cout,
             int M, int N, int K,
             int lda, int ldb, int ldc,
             long sA, long sB, long sC,
             float scale)
{
    constexpr int LDT = 72;
    __shared__ __align__(16) __hip_bfloat16 As[128 * LDT];
    __shared__ __align__(16) __hip_bfloat16 Bs[128 * LDT];

    const int z = blockIdx.z;
    A  += (long)z * sA;
    Bt += (long)z * sB;

    const int m0 = blockIdx.y * 128;
    const int n0 = blockIdx.x * 128;

    const int t   = threadIdx.x;
    const int w   = t >> 6;
    const int l15 = t & 15;
    const int lq  = (t & 63) >> 4;
    const int wm  = w >> 1;
    const int wn  = w & 1;

    int rA[4], cA[4];
#pragma unroll
    for (int i = 0; i < 4; ++i) {
        int q = t + 256 * i;
        rA[i] = q >> 3;
        cA[i] = q & 7;
    }

    floatx4 acc[4][4];
#pragma unroll
    for (int i = 0; i < 4; ++i)
#pragma unroll
        for (int j = 0; j < 4; ++j)
            acc[i][j] = (floatx4){0.f, 0.f, 0.f, 0.f};

    for (int k0 = 0; k0 < K; k0 += 64) {
        short8 va[4], vb[4];
#pragma unroll
        for (int i = 0; i < 4; ++i) {
            va[i] = *(const short8*)(A  + (long)(m0 + rA[i]) * lda + cA[i] * 8 + k0);
            vb[i] = *(const short8*)(Bt + (long)(n0 + rA[i]) * ldb + cA[i] * 8 + k0);
        }
        __syncthreads();   // prior iteration's fragment reads complete
#pragma unroll
        for (int i = 0; i < 4; ++i) {
            *(short8*)&As[rA[i] * LDT + cA[i] * 8] = va[i];
            *(short8*)&Bs[rA[i] * LDT + cA[i] * 8] = vb[i];
        }
        __syncthreads();   // staging visible

#pragma unroll
        for (int s = 0; s < 2; ++s) {
            short8 af[4], bf[4];
#pragma unroll
            for (int mt = 0; mt < 4; ++mt) {
                int r = wm * 64 + mt * 16 + l15;
                af[mt] = *(const short8*)&As[r * LDT + (s * 4 + lq) * 8];
            }
#pragma unroll
            for (int nt = 0; nt < 4; ++nt) {
                int r = wn * 64 + nt * 16 + l15;
                bf[nt] = *(const short8*)&Bs[r * LDT + (s * 4 + lq) * 8];
            }
#pragma unroll
            for (int mt = 0; mt < 4; ++mt)
#pragma unroll
                for (int nt = 0; nt < 4; ++nt)
                    acc[mt][nt] = __builtin_amdgcn_mfma_f32_16x16x32_bf16(
                        af[mt], bf[nt], acc[mt][nt], 0, 0, 0);
        }
    }

    // C/D layout: col = lane&15, row = quad*4 + reg   [m89/m91]
#pragma unroll
    for (int nt = 0; nt < 4; ++nt) {
        int n = n0 + wn * 64 + nt * 16 + l15;
        float bb = bias ? bias[n] : 0.f;
#pragma unroll
        for (int mt = 0; mt < 4; ++mt) {
            int mBase = m0 + wm * 64 + mt * 16 + lq * 4;
#pragma unroll
            for (int r = 0; r < 4; ++r) {
                float v = acc[mt][nt][r] * scale + bb;
                long idx = (long)z * sC + (long)(mBase + r) * ldc + n;
                if (OUT_BF16) ((__hip_bfloat16*)Cout)[idx] = __float2bfloat16(v);
                else          ((float*)Cout)[idx] = v;
            }
        }
    }
}

// ---------------------------------------------------------------------------
// elementwise fp32 -> bf16 cast, 4 elems/thread
// ---------------------------------------------------------------------------
__global__ __launch_bounds__(256)
void cast_f32_bf16(const float* __restrict__ src,
                   __hip_bfloat16* __restrict__ dst, long n)
{
    long i = ((long)blockIdx.x * 256 + threadIdx.x) * 4;
    if (i + 3 >= n) return;
    float4 v = *(const float4*)(src + i);
    union { short4v s; __hip_bfloat16 h[4]; } u;
    u.h[0] = __float2bfloat16(v.x);
    u.h[1] = __float2bfloat16(v.y);
    u.h[2] = __float2bfloat16(v.z);
    u.h[3] = __float2bfloat16(v.w);
    *(short4v*)(dst + i) = u.s;
}

// ---------------------------------------------------------------------------
// transpose + cast fp32 -> bf16: dst[c*R + r] = src[r*C + c]
// ---------------------------------------------------------------------------
__global__ __launch_bounds__(256)
void transpose_cast(const float* __restrict__ src,
                    __hip_bfloat16* __restrict__ dst, int R, int C)
{
    __shared__ float tile[32][33];
    const int c0 = blockIdx.x * 32, r0 = blockIdx.y * 32;
    const int tx = threadIdx.x, ty = threadIdx.y;   // (32, 8)
#pragma unroll
    for (int i = 0; i < 4; ++i)
        tile[ty + 8 * i][tx] = src[(long)(r0 + ty + 8 * i) * C + c0 + tx];
    __syncthreads();
#pragma unroll
    for (int i = 0; i < 4; ++i)
        dst[(long)(c0 + ty + 8 * i) * R + r0 + tx] =
            __float2bfloat16(tile[tx][ty + 8 * i]);
}

// ---------------------------------------------------------------------------
// batched bf16 transpose: dst[b][c][r] = src[b][r][c]
// ---------------------------------------------------------------------------
__global__ __launch_bounds__(256)
void transpose_bf16(const __hip_bfloat16* __restrict__ src,
                    __hip_bfloat16* __restrict__ dst,
                    int R, int C, long sStride, long dStride)
{
    __shared__ __hip_bfloat16 tile[32][33];
    src += (long)blockIdx.z * sStride;
    dst += (long)blockIdx.z * dStride;
    const int c0 = blockIdx.x * 32, r0 = blockIdx.y * 32;
    const int tx = threadIdx.x, ty = threadIdx.y;   // (32, 8)
#pragma unroll
    for (int i = 0; i < 4; ++i)
        tile[ty + 8 * i][tx] = src[(long)(r0 + ty + 8 * i) * C + c0 + tx];
    __syncthreads();
#pragma unroll
    for (int i = 0; i < 4; ++i)
        dst[(long)(c0 + ty + 8 * i) * R + r0 + tx] = tile[tx][ty + 8 * i];
}

// ---------------------------------------------------------------------------
// row softmax: read 2048 fp32 scores, write 2048 bf16 P into the SAME row's
// first half (row stride 8 KB = 4096 bf16). All reads complete before the
// sum-reduction barriers, so the in-row overwrite is race-free.
// ---------------------------------------------------------------------------
__global__ __launch_bounds__(256)
void softmax_rows(float* __restrict__ Sc)
{
    const int  t   = threadIdx.x;
    const long row = blockIdx.x;
    float* srow = Sc + row * 2048;
    __hip_bfloat16* prow = reinterpret_cast<__hip_bfloat16*>(Sc) + row * 4096;

    float v[8];
#pragma unroll
    for (int i = 0; i < 8; ++i)
        v[i] = srow[t + 256 * i];

    float mx = v[0];
#pragma unroll
    for (int i = 1; i < 8; ++i) mx = fmaxf(mx, v[i]);
#pragma unroll
    for (int off = 32; off > 0; off >>= 1)
        mx = fmaxf(mx, __shfl_xor(mx, off));
    __shared__ float redm[4];
    if ((t & 63) == 0) redm[t >> 6] = mx;
    __syncthreads();
    mx = fmaxf(fmaxf(redm[0], redm[1]), fmaxf(redm[2], redm[3]));

    float sum = 0.f;
#pragma unroll
    for (int i = 0; i < 8; ++i) {
        v[i] = __expf(v[i] - mx);
        sum += v[i];
    }
#pragma unroll
    for (int off = 32; off > 0; off >>= 1)
        sum += __shfl_xor(sum, off);
    __shared__ float reds[4];
    if ((t & 63) == 0) reds[t >> 6] = sum;
    __syncthreads();
    sum = reds[0] + reds[1] + reds[2] + reds[3];

    const float inv = 1.0f / sum;
#pragma unroll
    for (int i = 0; i < 8; ++i)
        prow[t + 256 * i] = __float2bfloat16(v[i] * inv);
}

// ---------------------------------------------------------------------------
// All inputs/outputs fp32 (per reference). B=4, S=2048, D=1024.
// ws layout (MB):  Q@0(16)  K@16(16)  VT@32(16)  xbf@48(16)  WT@64(8)  V@72(16)
//   Sc fp32 @48..112 — overlays xbf/WT/V, which are dead when scores run.
// total 112 MB.
// ---------------------------------------------------------------------------
extern "C" void kernel_launch(void* const* d_in, const int* in_sizes, int n_in,
                              void* d_out, int out_size, void* d_ws, size_t ws_size,
                              hipStream_t stream)
{
    const float* x  = (const float*)d_in[0];
    const float* Wq = (const float*)d_in[1];
    const float* bq = (const float*)d_in[2];
    const float* Wk = (const float*)d_in[3];
    const float* bk = (const float*)d_in[4];
    const float* Wv = (const float*)d_in[5];
    const float* bv = (const float*)d_in[6];

    char* ws = (char*)d_ws;
    const long MB = 1048576;
    __hip_bfloat16* Q   = (__hip_bfloat16*)(ws);
    __hip_bfloat16* Kp  = (__hip_bfloat16*)(ws + 16 * MB);
    __hip_bfloat16* VT  = (__hip_bfloat16*)(ws + 32 * MB);
    __hip_bfloat16* xbf = (__hip_bfloat16*)(ws + 48 * MB);
    __hip_bfloat16* WT  = (__hip_bfloat16*)(ws + 64 * MB);
    __hip_bfloat16* V   = (__hip_bfloat16*)(ws + 72 * MB);
    float*          Sc  = (float*)         (ws + 48 * MB);   // overlays xbf/WT/V

    // 1. cast x -> bf16 (8M elems)
    cast_f32_bf16<<<8192, 256, 0, stream>>>(x, xbf, 8388608L);

    // 2. W^T casts (Bt layout for x @ W)
    dim3 tb(32, 8);
    transpose_cast<<<dim3(32, 32), tb, 0, stream>>>(Wq, WT,           1024, 1024);
    transpose_cast<<<dim3(32, 32), tb, 0, stream>>>(Wk, WT + 1048576, 1024, 1024);
    transpose_cast<<<dim3(32, 32), tb, 0, stream>>>(Wv, WT + 2097152, 1024, 1024);

    // 3. Q/K/V projections: [8192,1024] x [1024,1024] -> bf16
    gemm_bt<true><<<dim3(8, 64, 1), 256, 0, stream>>>(xbf, WT,           bq, Q,
        8192, 1024, 1024, 1024, 1024, 1024, 0, 0, 0, 1.f);
    gemm_bt<true><<<dim3(8, 64, 1), 256, 0, stream>>>(xbf, WT + 1048576, bk, Kp,
        8192, 1024, 1024, 1024, 1024, 1024, 0, 0, 0, 1.f);
    gemm_bt<true><<<dim3(8, 64, 1), 256, 0, stream>>>(xbf, WT + 2097152, bv, V,
        8192, 1024, 1024, 1024, 1024, 1024, 0, 0, 0, 1.f);

    // 4. V^T per batch (Bt layout for P @ V) — must finish before Sc overlays V
    transpose_bf16<<<dim3(32, 64, 4), tb, 0, stream>>>(V, VT,
        2048, 1024, 2048L * 1024, 1024L * 2048);

    // 5. scores: Sc_b = Q_b K_b^T / sqrt(128), fp32
    gemm_bt<false><<<dim3(16, 16, 4), 256, 0, stream>>>(Q, Kp, nullptr, Sc,
        2048, 2048, 1024, 1024, 1024, 2048,
        2048L * 1024, 2048L * 1024, 2048L * 2048, 0.08838834764831845f);

    // 6. softmax fp32 -> bf16 P overlaid (row stride 4096 bf16)
    softmax_rows<<<8192, 256, 0, stream>>>(Sc);

    // 7. out_b = P_b V_b -> fp32 d_out
    gemm_bt<false><<<dim3(8, 16, 4), 256, 0, stream>>>(
        (const __hip_bfloat16*)Sc, VT, nullptr, (float*)d_out,
        2048, 1024, 2048, 4096, 2048, 1024,
        2048L * 4096, 1024L * 2048, 2048L * 1024, 1.f);
}

// Round 4
// 263.463 us; speedup vs baseline: 1.1307x; 1.1307x over previous
//
#include <hip/hip_runtime.h>
#include <hip/hip_bf16.h>
#include <hip/hip_fp16.h>
#include <math.h>

typedef __attribute__((ext_vector_type(8))) short    short8;
typedef __attribute__((ext_vector_type(8))) _Float16 half8;
typedef __attribute__((ext_vector_type(4))) short    short4v;
typedef __attribute__((ext_vector_type(4))) float    floatx4;

// async global->LDS, 16B per lane; LDS dest = wave-uniform base + lane*16
#define GLD16(gp, lp) __builtin_amdgcn_global_load_lds( \
    (__attribute__((address_space(1))) void*)(void*)(gp), \
    (__attribute__((address_space(3))) void*)(lp), 16, 0, 0)

// ---------------------------------------------------------------------------
// C[M,N] = scale * (A[M,K] * Bt[N,K]^T) + bias ; fp32 acc.
// IN_F16: 0 = bf16 inputs (mfma_..._bf16), 1 = fp16 inputs (mfma_..._f16)
// OUT_T : 0 = fp32, 1 = bf16, 2 = fp16
// m97 structure: 128x128 tile, 4 waves (2x2), 4x4 16x16x32 MFMA/wave, BK=64,
// global_load_lds width-16 staging, XOR chunk swizzle (LDS chunk c of row r
// holds global chunk c^(r&7)) so ds_read_b128 fragment reads are 2-way (free).
// ---------------------------------------------------------------------------
template <int IN_F16, int OUT_T>
__global__ __launch_bounds__(256, 2)
void gemm_bt(const unsigned short* __restrict__ A,
             const unsigned short* __restrict__ Bt,
             const float* __restrict__ bias,
             void* __restrict__ Cout,
             int lda, int ldb, int ldc, int K,
             long sA, long sB, long sC,
             float scale)
{
    __shared__ __align__(16) unsigned short As[128 * 64];
    __shared__ __align__(16) unsigned short Bs[128 * 64];

    const int z = blockIdx.z;
    A  += (long)z * sA;
    Bt += (long)z * sB;

    const int m0 = blockIdx.y * 128;
    const int n0 = blockIdx.x * 128;

    const int t   = threadIdx.x;
    const int w   = t >> 6;
    const int l15 = t & 15;
    const int lq  = (t & 63) >> 4;
    const int wm  = w >> 1;
    const int wn  = w & 1;

    // staging: LDS chunk cid=(r*8+c) <- global chunk (r, c^(r&7)); 16B chunks
    long gOffA[4], gOffB[4];
    int  lOff[4];
#pragma unroll
    for (int i = 0; i < 4; ++i) {
        int cid = i * 256 + t;            // 0..1023
        int r   = cid >> 3;
        int c   = cid & 7;
        int cg  = c ^ (r & 7);
        lOff[i]  = cid * 8;
        gOffA[i] = (long)(m0 + r) * lda + cg * 8;
        gOffB[i] = (long)(n0 + r) * ldb + cg * 8;
    }

    floatx4 acc[4][4];
#pragma unroll
    for (int i = 0; i < 4; ++i)
#pragma unroll
        for (int j = 0; j < 4; ++j)
            acc[i][j] = (floatx4){0.f, 0.f, 0.f, 0.f};

    for (int k0 = 0; k0 < K; k0 += 64) {
#pragma unroll
        for (int i = 0; i < 4; ++i) {
            GLD16(A  + gOffA[i] + k0, &As[lOff[i]]);
            GLD16(Bt + gOffB[i] + k0, &Bs[lOff[i]]);
        }
        __syncthreads();   // vmcnt drained -> staging visible

#pragma unroll
        for (int s = 0; s < 2; ++s) {
            short8 af[4], bf[4];
#pragma unroll
            for (int mt = 0; mt < 4; ++mt) {
                int r  = wm * 64 + mt * 16 + l15;
                int cc = (s * 4 + lq) ^ (r & 7);
                af[mt] = *(const short8*)&As[r * 64 + cc * 8];
            }
#pragma unroll
            for (int nt = 0; nt < 4; ++nt) {
                int r  = wn * 64 + nt * 16 + l15;
                int cc = (s * 4 + lq) ^ (r & 7);
                bf[nt] = *(const short8*)&Bs[r * 64 + cc * 8];
            }
#pragma unroll
            for (int mt = 0; mt < 4; ++mt)
#pragma unroll
                for (int nt = 0; nt < 4; ++nt) {
                    if (IN_F16)
                        acc[mt][nt] = __builtin_amdgcn_mfma_f32_16x16x32_f16(
                            __builtin_bit_cast(half8, af[mt]),
                            __builtin_bit_cast(half8, bf[nt]),
                            acc[mt][nt], 0, 0, 0);
                    else
                        acc[mt][nt] = __builtin_amdgcn_mfma_f32_16x16x32_bf16(
                            af[mt], bf[nt], acc[mt][nt], 0, 0, 0);
                }
        }
        __syncthreads();   // fragment reads done before next staging
    }

    // C/D layout: col = lane&15, row = quad*4 + reg  [m89/m91]
#pragma unroll
    for (int nt = 0; nt < 4; ++nt) {
        int n = n0 + wn * 64 + nt * 16 + l15;
        float bb = bias ? bias[n] : 0.f;
#pragma unroll
        for (int mt = 0; mt < 4; ++mt) {
            int mBase = m0 + wm * 64 + mt * 16 + lq * 4;
#pragma unroll
            for (int r = 0; r < 4; ++r) {
                float v = acc[mt][nt][r] * scale + bb;
                long idx = (long)z * sC + (long)(mBase + r) * ldc + n;
                if (OUT_T == 0)      ((float*)Cout)[idx]          = v;
                else if (OUT_T == 1) ((__hip_bfloat16*)Cout)[idx] = __float2bfloat16(v);
                else                 ((__half*)Cout)[idx]         = __float2half(v);
            }
        }
    }
}

// ---------------------------------------------------------------------------
__global__ __launch_bounds__(256)
void cast_f32_bf16(const float* __restrict__ src,
                   __hip_bfloat16* __restrict__ dst, long n)
{
    long i = ((long)blockIdx.x * 256 + threadIdx.x) * 4;
    if (i + 3 >= n) return;
    float4 v = *(const float4*)(src + i);
    union { short4v s; __hip_bfloat16 h[4]; } u;
    u.h[0] = __float2bfloat16(v.x);
    u.h[1] = __float2bfloat16(v.y);
    u.h[2] = __float2bfloat16(v.z);
    u.h[3] = __float2bfloat16(v.w);
    *(short4v*)(dst + i) = u.s;
}

// transpose + cast fp32 -> bf16: dst[c*R + r] = src[r*C + c]
__global__ __launch_bounds__(256)
void transpose_cast(const float* __restrict__ src,
                    __hip_bfloat16* __restrict__ dst, int R, int C)
{
    __shared__ float tile[32][33];
    const int c0 = blockIdx.x * 32, r0 = blockIdx.y * 32;
    const int tx = threadIdx.x, ty = threadIdx.y;   // (32, 8)
#pragma unroll
    for (int i = 0; i < 4; ++i)
        tile[ty + 8 * i][tx] = src[(long)(r0 + ty + 8 * i) * C + c0 + tx];
    __syncthreads();
#pragma unroll
    for (int i = 0; i < 4; ++i)
        dst[(long)(c0 + ty + 8 * i) * R + r0 + tx] =
            __float2bfloat16(tile[tx][ty + 8 * i]);
}

// batched transpose + cast bf16 -> fp16 (exact): dst[b][c][r] = src[b][r][c]
// src row stride ldS; dst [C][R] dense per batch.
__global__ __launch_bounds__(256)
void transpose_b2h(const __hip_bfloat16* __restrict__ src, int ldS,
                   __half* __restrict__ dst,
                   int R, int C, long sStride, long dStride)
{
    __shared__ __hip_bfloat16 tile[32][33];
    src += (long)blockIdx.z * sStride;
    dst += (long)blockIdx.z * dStride;
    const int c0 = blockIdx.x * 32, r0 = blockIdx.y * 32;
    const int tx = threadIdx.x, ty = threadIdx.y;   // (32, 8)
#pragma unroll
    for (int i = 0; i < 4; ++i)
        tile[ty + 8 * i][tx] = src[(long)(r0 + ty + 8 * i) * ldS + c0 + tx];
    __syncthreads();
#pragma unroll
    for (int i = 0; i < 4; ++i)
        dst[(long)(c0 + ty + 8 * i) * R + r0 + tx] =
            __float2half(__bfloat162float(tile[tx][ty + 8 * i]));
}

// concat 3 fp32 bias vectors of length 1024 -> [3072]
__global__ __launch_bounds__(256)
void bias_concat(const float* __restrict__ b0, const float* __restrict__ b1,
                 const float* __restrict__ b2, float* __restrict__ dst)
{
    int i = blockIdx.x * 256 + threadIdx.x;   // grid 12 x 256 = 3072
    dst[i] = (i < 1024) ? b0[i] : (i < 2048) ? b1[i - 1024] : b2[i - 2048];
}

// in-place row softmax over 2048 fp16 scores (dense, ld=2048)
__global__ __launch_bounds__(256)
void softmax_rows(__half* __restrict__ S)
{
    const int  t   = threadIdx.x;
    const long row = blockIdx.x;
    __half* srow = S + row * 2048;

    float v[8];
#pragma unroll
    for (int i = 0; i < 8; ++i)
        v[i] = __half2float(srow[t + 256 * i]);

    float mx = v[0];
#pragma unroll
    for (int i = 1; i < 8; ++i) mx = fmaxf(mx, v[i]);
#pragma unroll
    for (int off = 32; off > 0; off >>= 1)
        mx = fmaxf(mx, __shfl_xor(mx, off));
    __shared__ float redm[4];
    if ((t & 63) == 0) redm[t >> 6] = mx;
    __syncthreads();
    mx = fmaxf(fmaxf(redm[0], redm[1]), fmaxf(redm[2], redm[3]));

    float sum = 0.f;
#pragma unroll
    for (int i = 0; i < 8; ++i) {
        v[i] = __expf(v[i] - mx);
        sum += v[i];
    }
#pragma unroll
    for (int off = 32; off > 0; off >>= 1)
        sum += __shfl_xor(sum, off);
    __shared__ float reds[4];
    if ((t & 63) == 0) reds[t >> 6] = sum;
    __syncthreads();
    sum = reds[0] + reds[1] + reds[2] + reds[3];

    const float inv = 1.0f / sum;
#pragma unroll
    for (int i = 0; i < 8; ++i)
        srow[t + 256 * i] = __float2half(v[i] * inv);
}

// ---------------------------------------------------------------------------
// Inputs/outputs fp32. B=4, S=2048, D=1024.
// ws (MB): QKV bf16 [8192][3072] @0 (48) | VT fp16 @48 (16) | WT3 @64 (6)
//          biasCat @70 (12KB) | xbf @72 (16) | Sc fp16 @72 (32, overlays xbf
//          which is dead after the QKV GEMM). Total 104 MB.
// ---------------------------------------------------------------------------
extern "C" void kernel_launch(void* const* d_in, const int* in_sizes, int n_in,
                              void* d_out, int out_size, void* d_ws, size_t ws_size,
                              hipStream_t stream)
{
    const float* x  = (const float*)d_in[0];
    const float* Wq = (const float*)d_in[1];
    const float* bq = (const float*)d_in[2];
    const float* Wk = (const float*)d_in[3];
    const float* bk = (const float*)d_in[4];
    const float* Wv = (const float*)d_in[5];
    const float* bv = (const float*)d_in[6];

    char* ws = (char*)d_ws;
    const long MB = 1048576;
    __hip_bfloat16* QKV = (__hip_bfloat16*)(ws);             // [8192][3072]
    __half*         VT  = (__half*)        (ws + 48 * MB);   // 4 x [1024][2048]
    __hip_bfloat16* WT3 = (__hip_bfloat16*)(ws + 64 * MB);   // [3072][1024]
    float*          bc  = (float*)         (ws + 70 * MB);   // [3072]
    __hip_bfloat16* xbf = (__hip_bfloat16*)(ws + 72 * MB);   // [8192][1024]
    __half*         Sc  = (__half*)        (ws + 72 * MB);   // 4 x [2048][2048]

    dim3 tb(32, 8);
    // prep: cast x, build concatenated W^T and bias
    cast_f32_bf16<<<8192, 256, 0, stream>>>(x, xbf, 8388608L);
    transpose_cast<<<dim3(32, 32), tb, 0, stream>>>(Wq, WT3,           1024, 1024);
    transpose_cast<<<dim3(32, 32), tb, 0, stream>>>(Wk, WT3 + 1048576, 1024, 1024);
    transpose_cast<<<dim3(32, 32), tb, 0, stream>>>(Wv, WT3 + 2097152, 1024, 1024);
    bias_concat<<<12, 256, 0, stream>>>(bq, bk, bv, bc);

    // fused QKV projection: [8192,1024] x [1024,3072] -> bf16 QKV (ldc 3072)
    gemm_bt<0, 1><<<dim3(24, 64, 1), 256, 0, stream>>>(
        (const unsigned short*)xbf, (const unsigned short*)WT3, bc, QKV,
        1024, 1024, 3072, 1024, 0, 0, 0, 1.f);

    // V^T per batch (bf16 -> fp16, exact): V = QKV cols 2048..3071
    transpose_b2h<<<dim3(32, 64, 4), tb, 0, stream>>>(
        QKV + 2048, 3072, VT, 2048, 1024, 2048L * 3072, 1024L * 2048);

    // scores: Sc_b = Q_b K_b^T / sqrt(128) -> fp16 (overlays dead xbf)
    gemm_bt<0, 2><<<dim3(16, 16, 4), 256, 0, stream>>>(
        (const unsigned short*)QKV, (const unsigned short*)(QKV + 1024),
        nullptr, Sc,
        3072, 3072, 2048, 1024,
        2048L * 3072, 2048L * 3072, 2048L * 2048, 0.08838834764831845f);

    // softmax in place (fp16 -> fp16 P)
    softmax_rows<<<8192, 256, 0, stream>>>(Sc);

    // out_b = P_b V_b -> fp32 d_out (f16 MFMA path)
    gemm_bt<1, 0><<<dim3(8, 16, 4), 256, 0, stream>>>(
        (const unsigned short*)Sc, (const unsigned short*)VT, nullptr,
        (float*)d_out,
        2048, 2048, 1024, 2048,
        2048L * 2048, 1024L * 2048, 2048L * 1024, 1.f);
}

// Round 5
// 238.748 us; speedup vs baseline: 1.2478x; 1.1035x over previous
//
#include <hip/hip_runtime.h>
#include <hip/hip_bf16.h>
#include <math.h>

typedef __attribute__((ext_vector_type(8))) short  short8;
typedef __attribute__((ext_vector_type(4))) short  short4v;
typedef __attribute__((ext_vector_type(4))) float  floatx4;

// async global->LDS, 16B per lane; LDS dest = wave-uniform base + lane*16
#define GLD16(gp, lp) __builtin_amdgcn_global_load_lds( \
    (__attribute__((address_space(1))) void*)(void*)(gp), \
    (__attribute__((address_space(3))) void*)(lp), 16, 0, 0)

// ---------------------------------------------------------------------------
// Shared m97-style bf16 GEMM core: C = A[M,K] * Bt[N,K]^T, fp32 acc.
// 128x128 tile, 4 waves (2x2), 4x4 16x16x32 MFMA per wave, BK=64,
// global_load_lds width-16 staging, XOR chunk swizzle (chunk c of row r holds
// global chunk c^(r&7)) -> ds_read_b128 fragment reads are 2-way (free).
// MODE 1: QKV projection. +bias; n0<2048 -> bf16 C store; n0>=2048 -> V part,
//         written TRANSPOSED (via LDS bounce) into VT[b][d][s], bf16.
// MODE 2: scores. epilogue e=exp(acc*scale) -> bf16 Pu store + per-row
//         partial sums atomicAdd'ed into rowsum (offset-free softmax).
// MODE 3: PV. epilogue out = acc / rowsum[row], fp32 store.
// ---------------------------------------------------------------------------
template <int MODE>
__global__ __launch_bounds__(256, 2)
void gemm_bt(const unsigned short* __restrict__ A,
             const unsigned short* __restrict__ Bt,
             const float* __restrict__ bias,
             void* __restrict__ Cout,
             int lda, int ldb, int ldc, int K,
             long sA, long sB, long sC,
             float scale,
             unsigned short* __restrict__ VT,
             float* __restrict__ rowsum)
{
    __shared__ __align__(16) unsigned short smem[16384];   // 32 KB
    unsigned short* As = smem;
    unsigned short* Bs = smem + 8192;

    const int z = blockIdx.z;
    A  += (long)z * sA;
    Bt += (long)z * sB;

    const int m0 = blockIdx.y * 128;
    const int n0 = blockIdx.x * 128;

    const int t   = threadIdx.x;
    const int w   = t >> 6;
    const int l15 = t & 15;
    const int lq  = (t & 63) >> 4;
    const int wm  = w >> 1;
    const int wn  = w & 1;

    // staging: LDS chunk cid=(r*8+c) <- global chunk (r, c^(r&7)); 16B chunks
    long gOffA[4], gOffB[4];
    int  lOff[4];
#pragma unroll
    for (int i = 0; i < 4; ++i) {
        int cid = i * 256 + t;
        int r   = cid >> 3;
        int c   = cid & 7;
        int cg  = c ^ (r & 7);
        lOff[i]  = cid * 8;
        gOffA[i] = (long)(m0 + r) * lda + cg * 8;
        gOffB[i] = (long)(n0 + r) * ldb + cg * 8;
    }

    floatx4 acc[4][4];
#pragma unroll
    for (int i = 0; i < 4; ++i)
#pragma unroll
        for (int j = 0; j < 4; ++j)
            acc[i][j] = (floatx4){0.f, 0.f, 0.f, 0.f};

    for (int k0 = 0; k0 < K; k0 += 64) {
#pragma unroll
        for (int i = 0; i < 4; ++i) {
            GLD16(A  + gOffA[i] + k0, &As[lOff[i]]);
            GLD16(Bt + gOffB[i] + k0, &Bs[lOff[i]]);
        }
        __syncthreads();   // vmcnt drained -> staging visible

#pragma unroll
        for (int s = 0; s < 2; ++s) {
            short8 af[4], bf[4];
#pragma unroll
            for (int mt = 0; mt < 4; ++mt) {
                int r  = wm * 64 + mt * 16 + l15;
                int cc = (s * 4 + lq) ^ (r & 7);
                af[mt] = *(const short8*)&As[r * 64 + cc * 8];
            }
#pragma unroll
            for (int nt = 0; nt < 4; ++nt) {
                int r  = wn * 64 + nt * 16 + l15;
                int cc = (s * 4 + lq) ^ (r & 7);
                bf[nt] = *(const short8*)&Bs[r * 64 + cc * 8];
            }
#pragma unroll
            for (int mt = 0; mt < 4; ++mt)
#pragma unroll
                for (int nt = 0; nt < 4; ++nt)
                    acc[mt][nt] = __builtin_amdgcn_mfma_f32_16x16x32_bf16(
                        af[mt], bf[nt], acc[mt][nt], 0, 0, 0);
        }
        __syncthreads();   // fragment reads done before next staging
    }

    // ---------------- epilogues (C/D layout: col=lane&15, row=quad*4+reg) ----
    if (MODE == 1) {
        if (n0 < 2048) {
            // Q/K part: plain bf16 store with bias
#pragma unroll
            for (int nt = 0; nt < 4; ++nt) {
                int n = n0 + wn * 64 + nt * 16 + l15;
                float bb = bias[n];
#pragma unroll
                for (int mt = 0; mt < 4; ++mt) {
                    int mBase = m0 + wm * 64 + mt * 16 + lq * 4;
#pragma unroll
                    for (int r = 0; r < 4; ++r) {
                        float v = acc[mt][nt][r] + bb;
                        ((__hip_bfloat16*)Cout)[(long)(mBase + r) * ldc + n] =
                            __float2bfloat16(v);
                    }
                }
            }
        } else {
            // V part: transpose via LDS into VT[b][d][s] (d = n-2048, s = m%2048)
            const int  z2  = m0 >> 11;
            const int  s0l = m0 & 2047;
            const int  d0  = n0 - 2048;
            __hip_bfloat16* T = (__hip_bfloat16*)smem;   // [64][136]
#pragma unroll
            for (int p = 0; p < 2; ++p) {
                __syncthreads();
                if (wn == p) {
#pragma unroll
                    for (int nt = 0; nt < 4; ++nt) {
                        int nl = nt * 16 + l15;           // 0..63
                        float bb = bias[n0 + p * 64 + nl];
#pragma unroll
                        for (int mt = 0; mt < 4; ++mt)
#pragma unroll
                            for (int r = 0; r < 4; ++r) {
                                int ml = wm * 64 + mt * 16 + lq * 4 + r;
                                T[nl * 136 + ml] =
                                    __float2bfloat16(acc[mt][nt][r] + bb);
                            }
                    }
                }
                __syncthreads();
#pragma unroll
                for (int pass = 0; pass < 4; ++pass) {
                    int row = pass * 16 + (t >> 4);       // 0..63
                    int mc  = (t & 15) * 8;
                    short8 val = *(const short8*)&T[row * 136 + mc];
                    *(short8*)&VT[(long)z2 * (1024L * 2048) +
                                  (long)(d0 + p * 64 + row) * 2048 + s0l + mc] = val;
                }
            }
        }
    } else if (MODE == 2) {
        float* rs = rowsum + (long)z * 2048;
#pragma unroll
        for (int mt = 0; mt < 4; ++mt) {
#pragma unroll
            for (int r = 0; r < 4; ++r) {
                int m = m0 + wm * 64 + mt * 16 + lq * 4 + r;
                float psum = 0.f;
#pragma unroll
                for (int nt = 0; nt < 4; ++nt) {
                    int n = n0 + wn * 64 + nt * 16 + l15;
                    float e = __expf(acc[mt][nt][r] * scale);
                    __hip_bfloat16 eb = __float2bfloat16(e);
                    ((__hip_bfloat16*)Cout)[(long)z * sC + (long)m * ldc + n] = eb;
                    psum += __bfloat162float(eb);   // sum the rounded values
                }
                psum += __shfl_xor(psum, 1);
                psum += __shfl_xor(psum, 2);
                psum += __shfl_xor(psum, 4);
                psum += __shfl_xor(psum, 8);
                if (l15 == 0) atomicAdd(&rs[m], psum);
            }
        }
    } else {   // MODE 3
        const float* rs = rowsum + (long)z * 2048;
#pragma unroll
        for (int mt = 0; mt < 4; ++mt) {
            int mBase = m0 + wm * 64 + mt * 16 + lq * 4;
            float inv[4];
#pragma unroll
            for (int r = 0; r < 4; ++r) inv[r] = 1.0f / rs[mBase + r];
#pragma unroll
            for (int nt = 0; nt < 4; ++nt) {
                int n = n0 + wn * 64 + nt * 16 + l15;
#pragma unroll
                for (int r = 0; r < 4; ++r)
                    ((float*)Cout)[(long)z * sC + (long)(mBase + r) * ldc + n] =
                        acc[mt][nt][r] * inv[r];
            }
        }
    }
}

// ---------------------------------------------------------------------------
__global__ __launch_bounds__(256)
void cast_f32_bf16(const float* __restrict__ src,
                   __hip_bfloat16* __restrict__ dst, long n)
{
    long i = ((long)blockIdx.x * 256 + threadIdx.x) * 4;
    if (i + 3 >= n) return;
    float4 v = *(const float4*)(src + i);
    union { short4v s; __hip_bfloat16 h[4]; } u;
    u.h[0] = __float2bfloat16(v.x);
    u.h[1] = __float2bfloat16(v.y);
    u.h[2] = __float2bfloat16(v.z);
    u.h[3] = __float2bfloat16(v.w);
    *(short4v*)(dst + i) = u.s;
}

// transpose + cast fp32 -> bf16 for the 3 weight matrices (z picks source)
__global__ __launch_bounds__(256)
void transpose_cast3(const float* __restrict__ w0, const float* __restrict__ w1,
                     const float* __restrict__ w2, __hip_bfloat16* __restrict__ dst)
{
    __shared__ float tile[32][33];
    const int zz = blockIdx.z;
    const float* src = (zz == 0) ? w0 : (zz == 1) ? w1 : w2;
    dst += (long)zz * 1048576;
    const int c0 = blockIdx.x * 32, r0 = blockIdx.y * 32;
    const int tx = threadIdx.x, ty = threadIdx.y;   // (32, 8)
#pragma unroll
    for (int i = 0; i < 4; ++i)
        tile[ty + 8 * i][tx] = src[(long)(r0 + ty + 8 * i) * 1024 + c0 + tx];
    __syncthreads();
#pragma unroll
    for (int i = 0; i < 4; ++i)
        dst[(long)(c0 + ty + 8 * i) * 1024 + r0 + tx] =
            __float2bfloat16(tile[tx][ty + 8 * i]);
}

// concat 3 fp32 bias vectors of length 1024 -> [3072]
__global__ __launch_bounds__(256)
void bias_concat(const float* __restrict__ b0, const float* __restrict__ b1,
                 const float* __restrict__ b2, float* __restrict__ dst)
{
    int i = blockIdx.x * 256 + threadIdx.x;   // grid 12 x 256 = 3072
    dst[i] = (i < 1024) ? b0[i] : (i < 2048) ? b1[i - 1024] : b2[i - 2048];
}

// ---------------------------------------------------------------------------
// Inputs/outputs fp32. B=4, S=2048, D=1024.
// ws (MB): QKV bf16 [8192][3072] @0 (48) | VT bf16 4x[1024][2048] @48 (16)
//          WT3 @64 (6) | bc @70 (12KB) | rowsum @70+16KB (32KB)
//          xbf @72 (16) | Pu bf16 4x[2048][2048] @72 (32, overlays dead xbf)
// total 104 MB.
// ---------------------------------------------------------------------------
extern "C" void kernel_launch(void* const* d_in, const int* in_sizes, int n_in,
                              void* d_out, int out_size, void* d_ws, size_t ws_size,
                              hipStream_t stream)
{
    const float* x  = (const float*)d_in[0];
    const float* Wq = (const float*)d_in[1];
    const float* bq = (const float*)d_in[2];
    const float* Wk = (const float*)d_in[3];
    const float* bk = (const float*)d_in[4];
    const float* Wv = (const float*)d_in[5];
    const float* bv = (const float*)d_in[6];

    char* ws = (char*)d_ws;
    const long MB = 1048576;
    __hip_bfloat16* QKV = (__hip_bfloat16*)(ws);
    unsigned short* VT  = (unsigned short*)(ws + 48 * MB);
    __hip_bfloat16* WT3 = (__hip_bfloat16*)(ws + 64 * MB);
    float*          bc  = (float*)         (ws + 70 * MB);
    float*          rs  = (float*)         (ws + 70 * MB + 16384);
    __hip_bfloat16* xbf = (__hip_bfloat16*)(ws + 72 * MB);
    __hip_bfloat16* Pu  = (__hip_bfloat16*)(ws + 72 * MB);   // overlays xbf

    // prep
    cast_f32_bf16<<<8192, 256, 0, stream>>>(x, xbf, 8388608L);
    transpose_cast3<<<dim3(32, 32, 3), dim3(32, 8), 0, stream>>>(Wq, Wk, Wv, WT3);
    bias_concat<<<12, 256, 0, stream>>>(bq, bk, bv, bc);
    hipMemsetAsync(rs, 0, 8192 * sizeof(float), stream);

    // fused QKV projection (V part written transposed into VT)
    gemm_bt<1><<<dim3(24, 64, 1), 256, 0, stream>>>(
        (const unsigned short*)xbf, (const unsigned short*)WT3, bc, QKV,
        1024, 1024, 3072, 1024, 0, 0, 0, 1.f, VT, nullptr);

    // scores + exp + rowsum: Pu_b = exp(Q_b K_b^T / sqrt(128)), bf16
    gemm_bt<2><<<dim3(16, 16, 4), 256, 0, stream>>>(
        (const unsigned short*)QKV, (const unsigned short*)(QKV + 1024),
        nullptr, Pu,
        3072, 3072, 2048, 1024,
        2048L * 3072, 2048L * 3072, 2048L * 2048,
        0.08838834764831845f, nullptr, rs);

    // PV + normalize: out_b = (Pu_b V_b) / rowsum, fp32
    gemm_bt<3><<<dim3(8, 16, 4), 256, 0, stream>>>(
        (const unsigned short*)Pu, VT, nullptr, (float*)d_out,
        2048, 2048, 1024, 2048,
        2048L * 2048, 1024L * 2048, 2048L * 1024,
        1.f, nullptr, rs);
}